// Round 2
// baseline (1214.349 us; speedup 1.0000x reference)
//
#include <hip/hip_runtime.h>

#define BT 51200      // B*T
#define NB 512        // batch

// ---------- workspace float offsets ----------
#define P1_OFF   ((size_t)0)
#define X_OFF    ((size_t)20480000)
#define GX_OFF   ((size_t)0)
#define SM_OFF   ((size_t)27033600)

__device__ __forceinline__ float sigf(float x) {
  return __fdividef(1.f, 1.f + __expf(-x));
}
__device__ __forceinline__ float tanhf2(float x) {
  float ax = fabsf(x);
  float e = __expf(-2.f * ax);
  float r = __fdividef(1.f - e, 1.f + e);
  return x < 0.f ? -r : r;
}

// ================= K1: conv1 (SAME 3x3, C=4->16) + relu + 2x2 maxpool =====
__global__ __launch_bounds__(256, 2)
void k1_conv1(const float* __restrict__ obs, const float* __restrict__ w,
              const float* __restrict__ bias, float* __restrict__ p1) {
  int item = blockIdx.x * 256 + threadIdx.x;
  const float* xin = obs + (size_t)item * 400;
  float rows[4][4][12];
#pragma unroll 1
  for (int p = 0; p < 5; ++p) {
#pragma unroll
    for (int rr = 0; rr < 4; ++rr) {
      int r = 2 * p - 1 + rr;
      bool ok = (r >= 0) && (r <= 9);
#pragma unroll
      for (int c = 0; c < 4; ++c) {
        rows[rr][c][0] = 0.f;
        rows[rr][c][11] = 0.f;
        if (ok) {
#pragma unroll
          for (int j = 0; j < 10; ++j) rows[rr][c][j + 1] = xin[c * 100 + r * 10 + j];
        } else {
#pragma unroll
          for (int j = 0; j < 10; ++j) rows[rr][c][j + 1] = 0.f;
        }
      }
    }
#pragma unroll 1
    for (int o = 0; o < 16; ++o) {
      float bv = bias[o];
#pragma unroll
      for (int q = 0; q < 5; ++q) {
        float m = 0.f;  // relu folded into max
#pragma unroll
        for (int ii = 0; ii < 2; ++ii) {
#pragma unroll
          for (int jj = 0; jj < 2; ++jj) {
            float acc = bv;
#pragma unroll
            for (int c = 0; c < 4; ++c)
#pragma unroll
              for (int dr = 0; dr < 3; ++dr)
#pragma unroll
                for (int dj = 0; dj < 3; ++dj)
                  acc += rows[ii + dr][c][2 * q + jj + dj] * w[o * 36 + c * 9 + dr * 3 + dj];
            m = fmaxf(m, acc);
          }
        }
        p1[(size_t)(o * 25 + p * 5 + q) * BT + item] = m;
      }
    }
  }
}

// ================= K2: conv2 (SAME 3x3, 16->32) + relu + 2x2 maxpool ======
__global__ __launch_bounds__(256, 2)
void k2_conv2(const float* __restrict__ p1, const float* __restrict__ w,
              const float* __restrict__ bias, float* __restrict__ x) {
  int item = blockIdx.x * 256 + threadIdx.x;
#pragma unroll 1
  for (int oc = 0; oc < 4; ++oc) {
    float acc[8][16];
#pragma unroll
    for (int o = 0; o < 8; ++o) {
      float bv = bias[oc * 8 + o];
#pragma unroll
      for (int pos = 0; pos < 16; ++pos) acc[o][pos] = bv;
    }
#pragma unroll 1
    for (int c = 0; c < 16; ++c) {
      float in[6][6];
#pragma unroll
      for (int t = 0; t < 6; ++t) { in[0][t] = 0.f; in[t][0] = 0.f; }
#pragma unroll
      for (int i = 0; i < 5; ++i)
#pragma unroll
        for (int j = 0; j < 5; ++j)
          in[i + 1][j + 1] = p1[(size_t)(c * 25 + i * 5 + j) * BT + item];
#pragma unroll
      for (int o = 0; o < 8; ++o) {
#pragma unroll
        for (int i = 0; i < 4; ++i)
#pragma unroll
          for (int j = 0; j < 4; ++j) {
            float a = acc[o][i * 4 + j];
#pragma unroll
            for (int dr = 0; dr < 3; ++dr)
#pragma unroll
              for (int dj = 0; dj < 3; ++dj)
                a += in[i + dr][j + dj] * w[((oc * 8 + o) * 16 + c) * 9 + dr * 3 + dj];
            acc[o][i * 4 + j] = a;
          }
      }
    }
#pragma unroll
    for (int o = 0; o < 8; ++o)
#pragma unroll
      for (int p = 0; p < 2; ++p)
#pragma unroll
        for (int q = 0; q < 2; ++q) {
          float m = fmaxf(fmaxf(acc[o][(2 * p) * 4 + 2 * q], acc[o][(2 * p) * 4 + 2 * q + 1]),
                          fmaxf(acc[o][(2 * p + 1) * 4 + 2 * q], acc[o][(2 * p + 1) * 4 + 2 * q + 1]));
          m = fmaxf(m, 0.f);
          x[(size_t)((oc * 8 + o) * 4 + p * 2 + q) * BT + item] = m;
        }
  }
}

// ================= K3: fc1(+bn,relu) -> fc2(+bn,relu) -> eWih projection ===
__global__ __launch_bounds__(256, 2)
void k3_fc(const float* __restrict__ x,
           const float* __restrict__ f1w, const float* __restrict__ f1b,
           const float* __restrict__ bn1g, const float* __restrict__ bn1b,
           const float* __restrict__ f2w, const float* __restrict__ f2b,
           const float* __restrict__ bn2g, const float* __restrict__ bn2b,
           const float* __restrict__ eWih, const float* __restrict__ ebih,
           const float* __restrict__ ebhh, float* __restrict__ gx) {
  __shared__ float xs[128 * 64];
  __shared__ float ys[128 * 64];
  const float BNRS = 0.9999950000374997f;  // 1/sqrt(1+1e-5)
  int tid = threadIdx.x;
  int lane = tid & 63;
  int wv = __builtin_amdgcn_readfirstlane(tid >> 6);
  int i0 = blockIdx.x * 64;
#pragma unroll
  for (int r = 0; r < 32; ++r) {
    int k = r * 4 + (tid >> 6);
    xs[k * 64 + lane] = x[(size_t)k * BT + i0 + lane];
  }
  __syncthreads();
#pragma unroll 1
  for (int jj = 0; jj < 8; ++jj) {
    int j0 = wv * 32 + jj * 4;
    float a[4] = {0.f, 0.f, 0.f, 0.f};
#pragma unroll 8
    for (int k = 0; k < 128; ++k) {
      float xv = xs[k * 64 + lane];
#pragma unroll
      for (int u = 0; u < 4; ++u) a[u] += xv * f1w[(j0 + u) * 128 + k];
    }
#pragma unroll
    for (int u = 0; u < 4; ++u) {
      int j = j0 + u;
      float v = a[u] + f1b[j];
      v = bn1g[j] * v * BNRS + bn1b[j];
      ys[j * 64 + lane] = fmaxf(v, 0.f);
    }
  }
  __syncthreads();
#pragma unroll 1
  for (int jj = 0; jj < 4; ++jj) {
    int j0 = wv * 16 + jj * 4;
    float a[4] = {0.f, 0.f, 0.f, 0.f};
#pragma unroll 8
    for (int k = 0; k < 128; ++k) {
      float yv = ys[k * 64 + lane];
#pragma unroll
      for (int u = 0; u < 4; ++u) a[u] += yv * f2w[(j0 + u) * 128 + k];
    }
#pragma unroll
    for (int u = 0; u < 4; ++u) {
      int j = j0 + u;
      float v = a[u] + f2b[j];
      v = bn2g[j] * v * BNRS + bn2b[j];
      xs[j * 64 + lane] = fmaxf(v, 0.f);
    }
  }
  __syncthreads();
#pragma unroll 1
  for (int jj = 0; jj < 8; ++jj) {
    int j0 = wv * 32 + jj * 4;
    float a[4] = {0.f, 0.f, 0.f, 0.f};
#pragma unroll 8
    for (int k = 0; k < 64; ++k) {
      float zv = xs[k * 64 + lane];
#pragma unroll
      for (int u = 0; u < 4; ++u) a[u] += zv * eWih[(j0 + u) * 64 + k];
    }
#pragma unroll
    for (int u = 0; u < 4; ++u) {
      int j = j0 + u;
      gx[(size_t)j * BT + i0 + lane] = a[u] + ebih[j] + ebhh[j];
    }
  }
}

// ================= K4: encoder LSTM (T=100), one wave per batch ===========
// All cross-lane exchange via __shfl (register, race-free). LDS only holds
// the read-only transposed Whh.
__global__ __launch_bounds__(64, 4)
void k4_enc(const float* __restrict__ gx, const float* __restrict__ eWhh,
            float* __restrict__ dh, float* __restrict__ dc) {
  __shared__ float wT[32 * 128];  // [k][gate]
  int lane = threadIdx.x;
  int b = blockIdx.x;
#pragma unroll 1
  for (int r = 0; r < 64; ++r) {
    int idx = lane + r * 64;
    int g = idx & 127, k = idx >> 7;
    wT[k * 128 + g] = eWhh[g * 32 + k];
  }
  __syncthreads();
  float c = 0.f, h = 0.f;
  size_t base0 = (size_t)b * 100;
  float ga_n = gx[(size_t)lane * BT + base0];
  float gb_n = gx[(size_t)(lane + 64) * BT + base0];
  int xl = (lane & 31) + 32;
#pragma unroll 1
  for (int t = 0; t < 100; ++t) {
    float ga = ga_n, gb2 = gb_n;
    if (t < 99) {
      ga_n = gx[(size_t)lane * BT + base0 + t + 1];
      gb_n = gx[(size_t)(lane + 64) * BT + base0 + t + 1];
    }
#pragma unroll
    for (int k = 0; k < 32; ++k) {
      float hk = __shfl(h, k);
      ga += hk * wT[k * 128 + lane];
      gb2 += hk * wT[k * 128 + lane + 64];
    }
    float gaX = __shfl(ga, xl);   // gate lane+32 (f for lanes<32)
    float gbX = __shfl(gb2, xl);  // gate lane+96 (o for lanes<32)
    if (lane < 32) {
      float ig = sigf(ga);
      float fg = sigf(gaX);
      float gg = tanhf2(gb2);
      float og = sigf(gbX);
      c = fg * c + ig * gg;
      h = og * tanhf2(c);
    }
  }
  if (lane < 32) {
    dh[b * 32 + lane] = h;
    dc[b * 32 + lane] = c;
  }
}

// ====== K5: decoder LSTM (din==dh identity) + physics + Q/R LSTMs =========
__global__ __launch_bounds__(256, 2)
void k5_dec(const float* __restrict__ obs,
            const float* __restrict__ dWih, const float* __restrict__ dWhh,
            const float* __restrict__ dbih, const float* __restrict__ dbhh,
            const float* __restrict__ ow, const float* __restrict__ ob,
            const float* __restrict__ qWih, const float* __restrict__ qWhh,
            const float* __restrict__ qbih, const float* __restrict__ qbhh,
            const float* __restrict__ qfw, const float* __restrict__ qfb,
            const float* __restrict__ rWih, const float* __restrict__ rWhh,
            const float* __restrict__ rbih, const float* __restrict__ rbhh,
            const float* __restrict__ rfw, const float* __restrict__ rfb,
            const float* __restrict__ dh0, const float* __restrict__ dc0,
            float* __restrict__ traj, float* __restrict__ qdg, float* __restrict__ rdg) {
  __shared__ float dwT[32 * 128], qihT[24 * 128], qhhT[32 * 128], rihT[24 * 128], rhhT[32 * 128];
  __shared__ float owT[32 * 12], qfwT[32 * 24], rfwT[32 * 24];
  __shared__ float dbs[128], qbs[128], rbs[128];
  __shared__ float tL4[4 * 120];
  int tid = threadIdx.x;
  for (int idx = tid; idx < 4096; idx += 256) {
    int k = idx >> 7, g = idx & 127;
    dwT[idx] = dWih[g * 32 + k] + dWhh[g * 32 + k];  // din==dh every step
    qhhT[idx] = qWhh[g * 32 + k];
    rhhT[idx] = rWhh[g * 32 + k];
  }
  for (int idx = tid; idx < 3072; idx += 256) {
    int k = idx >> 7, g = idx & 127;
    qihT[idx] = qWih[g * 24 + k];
    rihT[idx] = rWih[g * 24 + k];
  }
  for (int idx = tid; idx < 384; idx += 256) {
    int k = idx / 12, j = idx - k * 12;
    owT[idx] = ow[j * 32 + k];
  }
  for (int idx = tid; idx < 768; idx += 256) {
    int k = idx / 24, j = idx - k * 24;
    qfwT[idx] = qfw[j * 32 + k];
    rfwT[idx] = rfw[j * 32 + k];
  }
  for (int idx = tid; idx < 128; idx += 256) {
    dbs[idx] = dbih[idx] + dbhh[idx];
    qbs[idx] = qbih[idx] + qbhh[idx];
    rbs[idx] = rbih[idx] + rbhh[idx];
  }
  __syncthreads();
  int lane = tid & 63, w = tid >> 6, b = blockIdx.x * 4 + w;
  float* tL = tL4 + w * 120;
  int xl = (lane & 31) + 32;
  int l12 = lane < 12 ? lane : 0;
  int l24 = lane < 24 ? lane : 0;
  float cc = 0.f, hh = 0.f;
  if (lane < 32) {
    hh = dh0[b * 32 + lane];
    cc = dc0[b * 32 + lane];
  }
  float aReg[5];
  // decoder: 5 steps
#pragma unroll 1
  for (int s = 0; s < 5; ++s) {
    float ga = dbs[lane], gb2 = dbs[lane + 64];
#pragma unroll
    for (int k = 0; k < 32; ++k) {
      float hk = __shfl(hh, k);
      ga += hk * dwT[k * 128 + lane];
      gb2 += hk * dwT[k * 128 + lane + 64];
    }
    float gaX = __shfl(ga, xl);
    float gbX = __shfl(gb2, xl);
    if (lane < 32) {
      float ig = sigf(ga), fg = sigf(gaX);
      float gg = tanhf2(gb2), og = sigf(gbX);
      cc = fg * cc + ig * gg;
      hh = og * tanhf2(cc);
    }
    float pa = ob[l12];
#pragma unroll
    for (int k = 0; k < 32; ++k) pa += __shfl(hh, k) * owT[k * 12 + l12];
    aReg[s] = pa;
  }
  // physics integration -> tL (traj)
  if (lane < 12) {
    int n = lane >> 1, d = lane & 1;
    float v0 = 0.f, p0 = 0.f;
    if (n == 0) {
      p0 = obs[(size_t)b * 40000 + 39600 + d];
      v0 = obs[(size_t)b * 40000 + 39600 + 2 + d];
    }
    float vc = v0, pc = p0;
#pragma unroll
    for (int s = 0; s < 5; ++s) {
      float a = aReg[s];
      vc += 0.1f * a;
      pc += vc * 0.1f + a * 0.005f;
      tL[s * 24 + n * 4 + d] = pc;
      tL[s * 24 + n * 4 + 2 + d] = vc;
    }
  }
  __syncthreads();
#pragma unroll
  for (int e = 0; e < 2; ++e) {
    int idx = lane + 64 * e;
    if (idx < 120) traj[(size_t)b * 120 + idx] = tL[idx];
  }
  // Q then R LSTM over traj
#pragma unroll 1
  for (int qr = 0; qr < 2; ++qr) {
    const float* ihT = qr ? rihT : qihT;
    const float* hhT = qr ? rhhT : qhhT;
    const float* bs = qr ? rbs : qbs;
    const float* fwT = qr ? rfwT : qfwT;
    const float* fbg = qr ? rfb : qfb;
    float* outg = qr ? rdg : qdg;
    hh = 0.f;
    cc = 0.f;
#pragma unroll 1
    for (int s = 0; s < 5; ++s) {
      float ga = bs[lane], gb2 = bs[lane + 64];
#pragma unroll
      for (int k = 0; k < 24; ++k) {
        float z = tL[s * 24 + k];
        ga += z * ihT[k * 128 + lane];
        gb2 += z * ihT[k * 128 + lane + 64];
      }
#pragma unroll
      for (int k = 0; k < 32; ++k) {
        float hk = __shfl(hh, k);
        ga += hk * hhT[k * 128 + lane];
        gb2 += hk * hhT[k * 128 + lane + 64];
      }
      float gaX = __shfl(ga, xl);
      float gbX = __shfl(gb2, xl);
      if (lane < 32) {
        float ig = sigf(ga), fg = sigf(gaX);
        float gg = tanhf2(gb2), og = sigf(gbX);
        cc = fg * cc + ig * gg;
        hh = og * tanhf2(cc);
      }
    }
    float qv = fbg[l24];
#pragma unroll
    for (int k = 0; k < 32; ++k) qv += __shfl(hh, k) * fwT[k * 24 + l24];
    if (lane < 24) outg[b * 24 + lane] = fabsf(qv);
  }
}

// ================= K6: Kalman filter, one wave per batch ==================
__global__ __launch_bounds__(64, 4)
void k6_kf(const float* __restrict__ obs, const float* __restrict__ traj,
           const float* __restrict__ qd, const float* __restrict__ rd,
           float* __restrict__ out) {
  __shared__ float Pa[600], Pb[600], ag[24 * 49], sL[24], sm[24], inn[24], qL[24], rL[24];
  int lane = threadIdx.x;
  int b = blockIdx.x;
  if (lane < 24) {
    sL[lane] = (lane < 4) ? obs[(size_t)b * 40000 + 39600 + lane] : 0.f;
    qL[lane] = qd[b * 24 + lane];
    rL[lane] = rd[b * 24 + lane];
  }
#pragma unroll
  for (int e = 0; e < 9; ++e) {
    int idx = lane + e * 64;
    if (idx < 576) {
      int i = idx / 24, j = idx - i * 24;
      Pa[i * 25 + j] = (i == j) ? 1.f : 0.f;
    }
  }
  __syncthreads();
  float* P = Pa;
  float* PN = Pb;
#pragma unroll 1
  for (int s = 0; s < 5; ++s) {
    // s_m = F s
    if (lane < 24) {
      float v = sL[lane];
      if ((lane & 3) < 2) v += 0.1f * sL[lane + 2];
      sm[lane] = v;
    }
    // P <- F P (rows i with i%4<2 += DT*row(i+2))
#pragma unroll
    for (int e = 0; e < 5; ++e) {
      int idx = lane + e * 64;
      if (idx < 288) {
        int r = idx / 24, j = idx - r * 24;
        int i = (r >> 1) * 4 + (r & 1);
        P[i * 25 + j] += 0.1f * P[(i + 2) * 25 + j];
      }
    }
    __syncthreads();
    // P <- P F^T (cols j with j%4<2 += DT*col(j+2))
#pragma unroll
    for (int e = 0; e < 5; ++e) {
      int idx = lane + e * 64;
      if (idx < 288) {
        int g = idx / 24, i = idx - g * 24;
        int jc = (g >> 1) * 4 + (g & 1);
        P[i * 25 + jc] += 0.1f * P[i * 25 + jc + 2];
      }
    }
    __syncthreads();
    if (lane < 24) P[lane * 25 + lane] += qL[lane];
    __syncthreads();
    // aug = [ S | Pm^T ],  S = Pm + diag(R)
#pragma unroll
    for (int e = 0; e < 18; ++e) {
      int idx = lane + e * 64;
      int i = idx / 48, j = idx - i * 48;
      float v;
      if (j < 24) {
        v = P[i * 25 + j];
        if (i == j) v += rL[i];
      } else {
        v = P[(j - 24) * 25 + i];
      }
      ag[i * 49 + j] = v;
    }
    __syncthreads();
    // Gauss-Jordan (S is SPD: no pivoting). lane = column.
    if (lane < 48) {
#pragma unroll 1
      for (int k = 0; k < 24; ++k) {
        float inv = 1.f / ag[k * 49 + k];
        float pk = ag[k * 49 + lane];
#pragma unroll 4
        for (int i = 0; i < 24; ++i) {
          float f = ag[i * 49 + k] * inv;
          float cur = ag[i * 49 + lane];
          float nv = (i == k) ? (pk * inv) : (cur - f * pk);
          ag[i * 49 + lane] = nv;
        }
      }
    }
    __syncthreads();
    // innovation
    if (lane < 24) inn[lane] = traj[(size_t)b * 120 + s * 24 + lane] - sm[lane];
    __syncthreads();
    // s update:  K[i][m] = Kt[m][i] = ag[m][24+i]
    if (lane < 24) {
      float acc = sm[lane];
#pragma unroll
      for (int m = 0; m < 24; ++m) acc += ag[m * 49 + 24 + lane] * inn[m];
      sL[lane] = acc;
      out[(size_t)b * 120 + s * 24 + lane] = acc;
    }
    // P_new = (I-K) Pm
#pragma unroll
    for (int e = 0; e < 9; ++e) {
      int idx = lane + e * 64;
      if (idx < 576) {
        int i = idx / 24, j = idx - i * 24;
        float acc = P[i * 25 + j];
#pragma unroll 4
        for (int k = 0; k < 24; ++k) acc -= ag[k * 49 + 24 + i] * P[k * 25 + j];
        PN[i * 25 + j] = acc;
      }
    }
    __syncthreads();
    float* tmp = P;
    P = PN;
    PN = tmp;
  }
}

// =========================================================================
extern "C" void kernel_launch(void* const* d_in, const int* in_sizes, int n_in,
                              void* d_out, int out_size, void* d_ws, size_t ws_size,
                              hipStream_t stream) {
  (void)in_sizes; (void)n_in; (void)out_size; (void)ws_size;
  const float* obs  = (const float*)d_in[0];
  const float* c1w  = (const float*)d_in[1];
  const float* c1b  = (const float*)d_in[2];
  const float* c2w  = (const float*)d_in[3];
  const float* c2b  = (const float*)d_in[4];
  const float* f1w  = (const float*)d_in[5];
  const float* f1b  = (const float*)d_in[6];
  const float* bn1g = (const float*)d_in[7];
  const float* bn1b = (const float*)d_in[8];
  const float* f2w  = (const float*)d_in[9];
  const float* f2b  = (const float*)d_in[10];
  const float* bn2g = (const float*)d_in[11];
  const float* bn2b = (const float*)d_in[12];
  const float* eWih = (const float*)d_in[13];
  const float* eWhh = (const float*)d_in[14];
  const float* ebih = (const float*)d_in[15];
  const float* ebhh = (const float*)d_in[16];
  const float* dWih = (const float*)d_in[17];
  const float* dWhh = (const float*)d_in[18];
  const float* dbih = (const float*)d_in[19];
  const float* dbhh = (const float*)d_in[20];
  const float* ow   = (const float*)d_in[21];
  const float* ob   = (const float*)d_in[22];
  const float* qWih = (const float*)d_in[23];
  const float* qWhh = (const float*)d_in[24];
  const float* qbih = (const float*)d_in[25];
  const float* qbhh = (const float*)d_in[26];
  const float* qfw  = (const float*)d_in[27];
  const float* qfb  = (const float*)d_in[28];
  const float* rWih = (const float*)d_in[29];
  const float* rWhh = (const float*)d_in[30];
  const float* rbih = (const float*)d_in[31];
  const float* rbhh = (const float*)d_in[32];
  const float* rfw  = (const float*)d_in[33];
  const float* rfb  = (const float*)d_in[34];

  float* ws = (float*)d_ws;
  float* p1   = ws + P1_OFF;
  float* x    = ws + X_OFF;
  float* gx   = ws + GX_OFF;       // reuses p1 region (dead after k2)
  float* dh   = ws + SM_OFF;
  float* dc   = dh + 16384;
  float* traj = dh + 32768;
  float* qdg  = dh + 94208;
  float* rdg  = dh + 106496;
  float* out  = (float*)d_out;

  k1_conv1<<<200, 256, 0, stream>>>(obs, c1w, c1b, p1);
  k2_conv2<<<200, 256, 0, stream>>>(p1, c2w, c2b, x);
  k3_fc<<<800, 256, 0, stream>>>(x, f1w, f1b, bn1g, bn1b, f2w, f2b, bn2g, bn2b,
                                 eWih, ebih, ebhh, gx);
  k4_enc<<<512, 64, 0, stream>>>(gx, eWhh, dh, dc);
  k5_dec<<<128, 256, 0, stream>>>(obs, dWih, dWhh, dbih, dbhh, ow, ob,
                                  qWih, qWhh, qbih, qbhh, qfw, qfb,
                                  rWih, rWhh, rbih, rbhh, rfw, rfb,
                                  dh, dc, traj, qdg, rdg);
  k6_kf<<<512, 64, 0, stream>>>(obs, traj, qdg, rdg, out);
}

// Round 3
// 884.392 us; speedup vs baseline: 1.3731x; 1.3731x over previous
//
#include <hip/hip_runtime.h>

#define BT 51200      // B*T
#define NB 512        // batch

// ---------- workspace float offsets ----------
#define P1_OFF   ((size_t)0)
#define X_OFF    ((size_t)20480000)
#define GX_OFF   ((size_t)0)
#define SM_OFF   ((size_t)27033600)

__device__ __forceinline__ float sigf(float x) {
  return __fdividef(1.f, 1.f + __expf(-x));
}
__device__ __forceinline__ float tanhf2(float x) {
  float ax = fabsf(x);
  float e = __expf(-2.f * ax);
  float r = __fdividef(1.f - e, 1.f + e);
  return x < 0.f ? -r : r;
}

// ================= K1: conv1 (SAME 3x3, C=4->16) + relu + 2x2 maxpool =====
// Block = 512 threads / 64 items. Stage 64x400 input into LDS coalesced;
// wave w computes output channels {2w, 2w+1}. Lane = item.
// LDS [item][401]: compute reads stride 401 (gcd(17,32)=1 -> 2-way max, free).
__global__ __launch_bounds__(512, 1)
void k1_conv1(const float* __restrict__ obs, const float* __restrict__ w,
              const float* __restrict__ bias, float* __restrict__ p1) {
  __shared__ float xs[64 * 401];
  int tid = threadIdx.x;
  int i0 = blockIdx.x * 64;
  for (int idx = tid; idx < 25600; idx += 512) {
    int item = idx / 400, feat = idx - item * 400;
    xs[item * 401 + feat] = obs[(size_t)(i0 + item) * 400 + feat];
  }
  __syncthreads();
  int lane = tid & 63;
  int wv = tid >> 6;  // 0..7, wave-uniform
  const float* xrow = xs + lane * 401;
#pragma unroll 1
  for (int p = 0; p < 5; ++p) {
    float acc[2][5][2][2];
#pragma unroll
    for (int u = 0; u < 2; ++u) {
      float bv = bias[wv * 2 + u];
#pragma unroll
      for (int q = 0; q < 5; ++q)
#pragma unroll
        for (int ii = 0; ii < 2; ++ii)
#pragma unroll
          for (int jj = 0; jj < 2; ++jj) acc[u][q][ii][jj] = bv;
    }
#pragma unroll 1
    for (int c = 0; c < 4; ++c) {
      float rows[4][12];
#pragma unroll
      for (int rr = 0; rr < 4; ++rr) {
        int r = 2 * p - 1 + rr;
        rows[rr][0] = 0.f;
        rows[rr][11] = 0.f;
        if (r >= 0 && r <= 9) {
#pragma unroll
          for (int j = 0; j < 10; ++j) rows[rr][j + 1] = xrow[c * 100 + r * 10 + j];
        } else {
#pragma unroll
          for (int j = 0; j < 10; ++j) rows[rr][j + 1] = 0.f;
        }
      }
#pragma unroll
      for (int u = 0; u < 2; ++u) {
        int o = wv * 2 + u;
        const float* wp = w + o * 36 + c * 9;
        float w00 = wp[0], w01 = wp[1], w02 = wp[2];
        float w10 = wp[3], w11 = wp[4], w12 = wp[5];
        float w20 = wp[6], w21 = wp[7], w22 = wp[8];
#pragma unroll
        for (int q = 0; q < 5; ++q) {
#pragma unroll
          for (int ii = 0; ii < 2; ++ii) {
#pragma unroll
            for (int jj = 0; jj < 2; ++jj) {
              float a = acc[u][q][ii][jj];
              int cb = 2 * q + jj;
              a += rows[ii][cb] * w00 + rows[ii][cb + 1] * w01 + rows[ii][cb + 2] * w02;
              a += rows[ii + 1][cb] * w10 + rows[ii + 1][cb + 1] * w11 + rows[ii + 1][cb + 2] * w12;
              a += rows[ii + 2][cb] * w20 + rows[ii + 2][cb + 1] * w21 + rows[ii + 2][cb + 2] * w22;
              acc[u][q][ii][jj] = a;
            }
          }
        }
      }
    }
#pragma unroll
    for (int u = 0; u < 2; ++u) {
      int o = wv * 2 + u;
#pragma unroll
      for (int q = 0; q < 5; ++q) {
        float m = fmaxf(fmaxf(acc[u][q][0][0], acc[u][q][0][1]),
                        fmaxf(acc[u][q][1][0], acc[u][q][1][1]));
        m = fmaxf(m, 0.f);
        p1[(size_t)(o * 25 + p * 5 + q) * BT + i0 + lane] = m;
      }
    }
  }
}

// ================= K2: conv2 (SAME 3x3, 16->32) + relu + 2x2 maxpool ======
// Grid (200, 4): blockIdx.y = output-channel group of 8. Thread = item.
__global__ __launch_bounds__(256, 2)
void k2_conv2(const float* __restrict__ p1, const float* __restrict__ w,
              const float* __restrict__ bias, float* __restrict__ x) {
  int item = blockIdx.x * 256 + threadIdx.x;
  int oc = blockIdx.y;
  float acc[8][16];
#pragma unroll
  for (int o = 0; o < 8; ++o) {
    float bv = bias[oc * 8 + o];
#pragma unroll
    for (int pos = 0; pos < 16; ++pos) acc[o][pos] = bv;
  }
#pragma unroll 1
  for (int c = 0; c < 16; ++c) {
    float in[6][6];
#pragma unroll
    for (int t = 0; t < 6; ++t) { in[0][t] = 0.f; in[t][0] = 0.f; }
#pragma unroll
    for (int i = 0; i < 5; ++i)
#pragma unroll
      for (int j = 0; j < 5; ++j)
        in[i + 1][j + 1] = p1[(size_t)(c * 25 + i * 5 + j) * BT + item];
#pragma unroll
    for (int o = 0; o < 8; ++o) {
#pragma unroll
      for (int i = 0; i < 4; ++i)
#pragma unroll
        for (int j = 0; j < 4; ++j) {
          float a = acc[o][i * 4 + j];
#pragma unroll
          for (int dr = 0; dr < 3; ++dr)
#pragma unroll
            for (int dj = 0; dj < 3; ++dj)
              a += in[i + dr][j + dj] * w[((oc * 8 + o) * 16 + c) * 9 + dr * 3 + dj];
          acc[o][i * 4 + j] = a;
        }
    }
  }
#pragma unroll
  for (int o = 0; o < 8; ++o)
#pragma unroll
    for (int p = 0; p < 2; ++p)
#pragma unroll
      for (int q = 0; q < 2; ++q) {
        float m = fmaxf(fmaxf(acc[o][(2 * p) * 4 + 2 * q], acc[o][(2 * p) * 4 + 2 * q + 1]),
                        fmaxf(acc[o][(2 * p + 1) * 4 + 2 * q], acc[o][(2 * p + 1) * 4 + 2 * q + 1]));
        m = fmaxf(m, 0.f);
        x[(size_t)((oc * 8 + o) * 4 + p * 2 + q) * BT + item] = m;
      }
}

// ================= K3: fc1(+bn,relu) -> fc2(+bn,relu) -> eWih projection ===
__global__ __launch_bounds__(256, 2)
void k3_fc(const float* __restrict__ x,
           const float* __restrict__ f1w, const float* __restrict__ f1b,
           const float* __restrict__ bn1g, const float* __restrict__ bn1b,
           const float* __restrict__ f2w, const float* __restrict__ f2b,
           const float* __restrict__ bn2g, const float* __restrict__ bn2b,
           const float* __restrict__ eWih, const float* __restrict__ ebih,
           const float* __restrict__ ebhh, float* __restrict__ gx) {
  __shared__ float xs[128 * 64];
  __shared__ float ys[128 * 64];
  const float BNRS = 0.9999950000374997f;  // 1/sqrt(1+1e-5)
  int tid = threadIdx.x;
  int lane = tid & 63;
  int wv = __builtin_amdgcn_readfirstlane(tid >> 6);
  int i0 = blockIdx.x * 64;
#pragma unroll
  for (int r = 0; r < 32; ++r) {
    int k = r * 4 + (tid >> 6);
    xs[k * 64 + lane] = x[(size_t)k * BT + i0 + lane];
  }
  __syncthreads();
#pragma unroll 1
  for (int jj = 0; jj < 8; ++jj) {
    int j0 = wv * 32 + jj * 4;
    float a[4] = {0.f, 0.f, 0.f, 0.f};
#pragma unroll 8
    for (int k = 0; k < 128; ++k) {
      float xv = xs[k * 64 + lane];
#pragma unroll
      for (int u = 0; u < 4; ++u) a[u] += xv * f1w[(j0 + u) * 128 + k];
    }
#pragma unroll
    for (int u = 0; u < 4; ++u) {
      int j = j0 + u;
      float v = a[u] + f1b[j];
      v = bn1g[j] * v * BNRS + bn1b[j];
      ys[j * 64 + lane] = fmaxf(v, 0.f);
    }
  }
  __syncthreads();
#pragma unroll 1
  for (int jj = 0; jj < 4; ++jj) {
    int j0 = wv * 16 + jj * 4;
    float a[4] = {0.f, 0.f, 0.f, 0.f};
#pragma unroll 8
    for (int k = 0; k < 128; ++k) {
      float yv = ys[k * 64 + lane];
#pragma unroll
      for (int u = 0; u < 4; ++u) a[u] += yv * f2w[(j0 + u) * 128 + k];
    }
#pragma unroll
    for (int u = 0; u < 4; ++u) {
      int j = j0 + u;
      float v = a[u] + f2b[j];
      v = bn2g[j] * v * BNRS + bn2b[j];
      xs[j * 64 + lane] = fmaxf(v, 0.f);
    }
  }
  __syncthreads();
#pragma unroll 1
  for (int jj = 0; jj < 8; ++jj) {
    int j0 = wv * 32 + jj * 4;
    float a[4] = {0.f, 0.f, 0.f, 0.f};
#pragma unroll 8
    for (int k = 0; k < 64; ++k) {
      float zv = xs[k * 64 + lane];
#pragma unroll
      for (int u = 0; u < 4; ++u) a[u] += zv * eWih[(j0 + u) * 64 + k];
    }
#pragma unroll
    for (int u = 0; u < 4; ++u) {
      int j = j0 + u;
      gx[(size_t)j * BT + i0 + lane] = a[u] + ebih[j] + ebhh[j];
    }
  }
}

// ================= K4: encoder LSTM (T=100), one wave per batch ===========
__global__ __launch_bounds__(64, 4)
void k4_enc(const float* __restrict__ gx, const float* __restrict__ eWhh,
            float* __restrict__ dh, float* __restrict__ dc) {
  __shared__ float wT[32 * 128];  // [k][gate]
  int lane = threadIdx.x;
  int b = blockIdx.x;
#pragma unroll 1
  for (int r = 0; r < 64; ++r) {
    int idx = lane + r * 64;
    int g = idx & 127, k = idx >> 7;
    wT[k * 128 + g] = eWhh[g * 32 + k];
  }
  __syncthreads();
  float c = 0.f, h = 0.f;
  size_t base0 = (size_t)b * 100;
  float ga_n = gx[(size_t)lane * BT + base0];
  float gb_n = gx[(size_t)(lane + 64) * BT + base0];
  int xl = (lane & 31) + 32;
#pragma unroll 1
  for (int t = 0; t < 100; ++t) {
    float ga = ga_n, gb2 = gb_n;
    if (t < 99) {
      ga_n = gx[(size_t)lane * BT + base0 + t + 1];
      gb_n = gx[(size_t)(lane + 64) * BT + base0 + t + 1];
    }
#pragma unroll
    for (int k = 0; k < 32; ++k) {
      float hk = __shfl(h, k);
      ga += hk * wT[k * 128 + lane];
      gb2 += hk * wT[k * 128 + lane + 64];
    }
    float gaX = __shfl(ga, xl);   // gate lane+32 (f for lanes<32)
    float gbX = __shfl(gb2, xl);  // gate lane+96 (o for lanes<32)
    if (lane < 32) {
      float ig = sigf(ga);
      float fg = sigf(gaX);
      float gg = tanhf2(gb2);
      float og = sigf(gbX);
      c = fg * c + ig * gg;
      h = og * tanhf2(c);
    }
  }
  if (lane < 32) {
    dh[b * 32 + lane] = h;
    dc[b * 32 + lane] = c;
  }
}

// ====== K5: decoder LSTM (din==dh identity) + physics + Q/R LSTMs =========
__global__ __launch_bounds__(256, 2)
void k5_dec(const float* __restrict__ obs,
            const float* __restrict__ dWih, const float* __restrict__ dWhh,
            const float* __restrict__ dbih, const float* __restrict__ dbhh,
            const float* __restrict__ ow, const float* __restrict__ ob,
            const float* __restrict__ qWih, const float* __restrict__ qWhh,
            const float* __restrict__ qbih, const float* __restrict__ qbhh,
            const float* __restrict__ qfw, const float* __restrict__ qfb,
            const float* __restrict__ rWih, const float* __restrict__ rWhh,
            const float* __restrict__ rbih, const float* __restrict__ rbhh,
            const float* __restrict__ rfw, const float* __restrict__ rfb,
            const float* __restrict__ dh0, const float* __restrict__ dc0,
            float* __restrict__ traj, float* __restrict__ qdg, float* __restrict__ rdg) {
  __shared__ float dwT[32 * 128], qihT[24 * 128], qhhT[32 * 128], rihT[24 * 128], rhhT[32 * 128];
  __shared__ float owT[32 * 12], qfwT[32 * 24], rfwT[32 * 24];
  __shared__ float dbs[128], qbs[128], rbs[128];
  __shared__ float tL4[4 * 120];
  int tid = threadIdx.x;
  for (int idx = tid; idx < 4096; idx += 256) {
    int k = idx >> 7, g = idx & 127;
    dwT[idx] = dWih[g * 32 + k] + dWhh[g * 32 + k];  // din==dh every step
    qhhT[idx] = qWhh[g * 32 + k];
    rhhT[idx] = rWhh[g * 32 + k];
  }
  for (int idx = tid; idx < 3072; idx += 256) {
    int k = idx >> 7, g = idx & 127;
    qihT[idx] = qWih[g * 24 + k];
    rihT[idx] = rWih[g * 24 + k];
  }
  for (int idx = tid; idx < 384; idx += 256) {
    int k = idx / 12, j = idx - k * 12;
    owT[idx] = ow[j * 32 + k];
  }
  for (int idx = tid; idx < 768; idx += 256) {
    int k = idx / 24, j = idx - k * 24;
    qfwT[idx] = qfw[j * 32 + k];
    rfwT[idx] = rfw[j * 32 + k];
  }
  for (int idx = tid; idx < 128; idx += 256) {
    dbs[idx] = dbih[idx] + dbhh[idx];
    qbs[idx] = qbih[idx] + qbhh[idx];
    rbs[idx] = rbih[idx] + rbhh[idx];
  }
  __syncthreads();
  int lane = tid & 63, w = tid >> 6, b = blockIdx.x * 4 + w;
  float* tL = tL4 + w * 120;
  int xl = (lane & 31) + 32;
  int l12 = lane < 12 ? lane : 0;
  int l24 = lane < 24 ? lane : 0;
  float cc = 0.f, hh = 0.f;
  if (lane < 32) {
    hh = dh0[b * 32 + lane];
    cc = dc0[b * 32 + lane];
  }
  float aReg[5];
  // decoder: 5 steps
#pragma unroll 1
  for (int s = 0; s < 5; ++s) {
    float ga = dbs[lane], gb2 = dbs[lane + 64];
#pragma unroll
    for (int k = 0; k < 32; ++k) {
      float hk = __shfl(hh, k);
      ga += hk * dwT[k * 128 + lane];
      gb2 += hk * dwT[k * 128 + lane + 64];
    }
    float gaX = __shfl(ga, xl);
    float gbX = __shfl(gb2, xl);
    if (lane < 32) {
      float ig = sigf(ga), fg = sigf(gaX);
      float gg = tanhf2(gb2), og = sigf(gbX);
      cc = fg * cc + ig * gg;
      hh = og * tanhf2(cc);
    }
    float pa = ob[l12];
#pragma unroll
    for (int k = 0; k < 32; ++k) pa += __shfl(hh, k) * owT[k * 12 + l12];
    aReg[s] = pa;
  }
  // physics integration -> tL (traj)
  if (lane < 12) {
    int n = lane >> 1, d = lane & 1;
    float v0 = 0.f, p0 = 0.f;
    if (n == 0) {
      p0 = obs[(size_t)b * 40000 + 39600 + d];
      v0 = obs[(size_t)b * 40000 + 39600 + 2 + d];
    }
    float vc = v0, pc = p0;
#pragma unroll
    for (int s = 0; s < 5; ++s) {
      float a = aReg[s];
      vc += 0.1f * a;
      pc += vc * 0.1f + a * 0.005f;
      tL[s * 24 + n * 4 + d] = pc;
      tL[s * 24 + n * 4 + 2 + d] = vc;
    }
  }
  __syncthreads();
#pragma unroll
  for (int e = 0; e < 2; ++e) {
    int idx = lane + 64 * e;
    if (idx < 120) traj[(size_t)b * 120 + idx] = tL[idx];
  }
  // Q then R LSTM over traj
#pragma unroll 1
  for (int qr = 0; qr < 2; ++qr) {
    const float* ihT = qr ? rihT : qihT;
    const float* hhT = qr ? rhhT : qhhT;
    const float* bs = qr ? rbs : qbs;
    const float* fwT = qr ? rfwT : qfwT;
    const float* fbg = qr ? rfb : qfb;
    float* outg = qr ? rdg : qdg;
    hh = 0.f;
    cc = 0.f;
#pragma unroll 1
    for (int s = 0; s < 5; ++s) {
      float ga = bs[lane], gb2 = bs[lane + 64];
#pragma unroll
      for (int k = 0; k < 24; ++k) {
        float z = tL[s * 24 + k];
        ga += z * ihT[k * 128 + lane];
        gb2 += z * ihT[k * 128 + lane + 64];
      }
#pragma unroll
      for (int k = 0; k < 32; ++k) {
        float hk = __shfl(hh, k);
        ga += hk * hhT[k * 128 + lane];
        gb2 += hk * hhT[k * 128 + lane + 64];
      }
      float gaX = __shfl(ga, xl);
      float gbX = __shfl(gb2, xl);
      if (lane < 32) {
        float ig = sigf(ga), fg = sigf(gaX);
        float gg = tanhf2(gb2), og = sigf(gbX);
        cc = fg * cc + ig * gg;
        hh = og * tanhf2(cc);
      }
    }
    float qv = fbg[l24];
#pragma unroll
    for (int k = 0; k < 32; ++k) qv += __shfl(hh, k) * fwT[k * 24 + l24];
    if (lane < 24) outg[b * 24 + lane] = fabsf(qv);
  }
}

// ================= K6: Kalman filter, one wave per batch ==================
__global__ __launch_bounds__(64, 4)
void k6_kf(const float* __restrict__ obs, const float* __restrict__ traj,
           const float* __restrict__ qd, const float* __restrict__ rd,
           float* __restrict__ out) {
  __shared__ float Pa[600], Pb[600], ag[24 * 49], sL[24], sm[24], inn[24], qL[24], rL[24];
  int lane = threadIdx.x;
  int b = blockIdx.x;
  if (lane < 24) {
    sL[lane] = (lane < 4) ? obs[(size_t)b * 40000 + 39600 + lane] : 0.f;
    qL[lane] = qd[b * 24 + lane];
    rL[lane] = rd[b * 24 + lane];
  }
#pragma unroll
  for (int e = 0; e < 9; ++e) {
    int idx = lane + e * 64;
    if (idx < 576) {
      int i = idx / 24, j = idx - i * 24;
      Pa[i * 25 + j] = (i == j) ? 1.f : 0.f;
    }
  }
  __syncthreads();
  float* P = Pa;
  float* PN = Pb;
#pragma unroll 1
  for (int s = 0; s < 5; ++s) {
    // s_m = F s
    if (lane < 24) {
      float v = sL[lane];
      if ((lane & 3) < 2) v += 0.1f * sL[lane + 2];
      sm[lane] = v;
    }
    // P <- F P
#pragma unroll
    for (int e = 0; e < 5; ++e) {
      int idx = lane + e * 64;
      if (idx < 288) {
        int r = idx / 24, j = idx - r * 24;
        int i = (r >> 1) * 4 + (r & 1);
        P[i * 25 + j] += 0.1f * P[(i + 2) * 25 + j];
      }
    }
    __syncthreads();
    // P <- P F^T
#pragma unroll
    for (int e = 0; e < 5; ++e) {
      int idx = lane + e * 64;
      if (idx < 288) {
        int g = idx / 24, i = idx - g * 24;
        int jc = (g >> 1) * 4 + (g & 1);
        P[i * 25 + jc] += 0.1f * P[i * 25 + jc + 2];
      }
    }
    __syncthreads();
    if (lane < 24) P[lane * 25 + lane] += qL[lane];
    __syncthreads();
    // aug = [ S | Pm^T ],  S = Pm + diag(R)
#pragma unroll
    for (int e = 0; e < 18; ++e) {
      int idx = lane + e * 64;
      int i = idx / 48, j = idx - i * 48;
      float v;
      if (j < 24) {
        v = P[i * 25 + j];
        if (i == j) v += rL[i];
      } else {
        v = P[(j - 24) * 25 + i];
      }
      ag[i * 49 + j] = v;
    }
    __syncthreads();
    // Gauss-Jordan (S is SPD: no pivoting). lane = column.
    if (lane < 48) {
#pragma unroll 1
      for (int k = 0; k < 24; ++k) {
        float inv = 1.f / ag[k * 49 + k];
        float pk = ag[k * 49 + lane];
#pragma unroll 4
        for (int i = 0; i < 24; ++i) {
          float f = ag[i * 49 + k] * inv;
          float cur = ag[i * 49 + lane];
          float nv = (i == k) ? (pk * inv) : (cur - f * pk);
          ag[i * 49 + lane] = nv;
        }
      }
    }
    __syncthreads();
    // innovation
    if (lane < 24) inn[lane] = traj[(size_t)b * 120 + s * 24 + lane] - sm[lane];
    __syncthreads();
    // s update:  K[i][m] = Kt[m][i] = ag[m][24+i]
    if (lane < 24) {
      float acc = sm[lane];
#pragma unroll
      for (int m = 0; m < 24; ++m) acc += ag[m * 49 + 24 + lane] * inn[m];
      sL[lane] = acc;
      out[(size_t)b * 120 + s * 24 + lane] = acc;
    }
    // P_new = (I-K) Pm
#pragma unroll
    for (int e = 0; e < 9; ++e) {
      int idx = lane + e * 64;
      if (idx < 576) {
        int i = idx / 24, j = idx - i * 24;
        float acc = P[i * 25 + j];
#pragma unroll 4
        for (int k = 0; k < 24; ++k) acc -= ag[k * 49 + 24 + i] * P[k * 25 + j];
        PN[i * 25 + j] = acc;
      }
    }
    __syncthreads();
    float* tmp = P;
    P = PN;
    PN = tmp;
  }
}

// =========================================================================
extern "C" void kernel_launch(void* const* d_in, const int* in_sizes, int n_in,
                              void* d_out, int out_size, void* d_ws, size_t ws_size,
                              hipStream_t stream) {
  (void)in_sizes; (void)n_in; (void)out_size; (void)ws_size;
  const float* obs  = (const float*)d_in[0];
  const float* c1w  = (const float*)d_in[1];
  const float* c1b  = (const float*)d_in[2];
  const float* c2w  = (const float*)d_in[3];
  const float* c2b  = (const float*)d_in[4];
  const float* f1w  = (const float*)d_in[5];
  const float* f1b  = (const float*)d_in[6];
  const float* bn1g = (const float*)d_in[7];
  const float* bn1b = (const float*)d_in[8];
  const float* f2w  = (const float*)d_in[9];
  const float* f2b  = (const float*)d_in[10];
  const float* bn2g = (const float*)d_in[11];
  const float* bn2b = (const float*)d_in[12];
  const float* eWih = (const float*)d_in[13];
  const float* eWhh = (const float*)d_in[14];
  const float* ebih = (const float*)d_in[15];
  const float* ebhh = (const float*)d_in[16];
  const float* dWih = (const float*)d_in[17];
  const float* dWhh = (const float*)d_in[18];
  const float* dbih = (const float*)d_in[19];
  const float* dbhh = (const float*)d_in[20];
  const float* ow   = (const float*)d_in[21];
  const float* ob   = (const float*)d_in[22];
  const float* qWih = (const float*)d_in[23];
  const float* qWhh = (const float*)d_in[24];
  const float* qbih = (const float*)d_in[25];
  const float* qbhh = (const float*)d_in[26];
  const float* qfw  = (const float*)d_in[27];
  const float* qfb  = (const float*)d_in[28];
  const float* rWih = (const float*)d_in[29];
  const float* rWhh = (const float*)d_in[30];
  const float* rbih = (const float*)d_in[31];
  const float* rbhh = (const float*)d_in[32];
  const float* rfw  = (const float*)d_in[33];
  const float* rfb  = (const float*)d_in[34];

  float* ws = (float*)d_ws;
  float* p1   = ws + P1_OFF;
  float* x    = ws + X_OFF;
  float* gx   = ws + GX_OFF;       // reuses p1 region (dead after k2)
  float* dh   = ws + SM_OFF;
  float* dc   = dh + 16384;
  float* traj = dh + 32768;
  float* qdg  = dh + 94208;
  float* rdg  = dh + 106496;
  float* out  = (float*)d_out;

  k1_conv1<<<800, 512, 0, stream>>>(obs, c1w, c1b, p1);
  k2_conv2<<<dim3(200, 4), 256, 0, stream>>>(p1, c2w, c2b, x);
  k3_fc<<<800, 256, 0, stream>>>(x, f1w, f1b, bn1g, bn1b, f2w, f2b, bn2g, bn2b,
                                 eWih, ebih, ebhh, gx);
  k4_enc<<<512, 64, 0, stream>>>(gx, eWhh, dh, dc);
  k5_dec<<<128, 256, 0, stream>>>(obs, dWih, dWhh, dbih, dbhh, ow, ob,
                                  qWih, qWhh, qbih, qbhh, qfw, qfb,
                                  rWih, rWhh, rbih, rbhh, rfw, rfb,
                                  dh, dc, traj, qdg, rdg);
  k6_kf<<<512, 64, 0, stream>>>(obs, traj, qdg, rdg, out);
}

// Round 4
// 737.680 us; speedup vs baseline: 1.6462x; 1.1989x over previous
//
#include <hip/hip_runtime.h>

#define BT 51200      // B*T
#define NB 512        // batch

// ---------- workspace float offsets ----------
#define P1_OFF   ((size_t)0)
#define X_OFF    ((size_t)20480000)
#define GX_OFF   ((size_t)0)
#define SM_OFF   ((size_t)27033600)

__device__ __forceinline__ float sigf(float x) {
  return __fdividef(1.f, 1.f + __expf(-x));
}
__device__ __forceinline__ float tanhf2(float x) {
  float ax = fabsf(x);
  float e = __expf(-2.f * ax);
  float r = __fdividef(1.f - e, 1.f + e);
  return x < 0.f ? -r : r;
}

// ================= K1: conv1 (SAME 3x3, C=4->16) + relu + 2x2 maxpool =====
__global__ __launch_bounds__(512, 1)
void k1_conv1(const float* __restrict__ obs, const float* __restrict__ w,
              const float* __restrict__ bias, float* __restrict__ p1) {
  __shared__ float xs[64 * 401];
  int tid = threadIdx.x;
  int i0 = blockIdx.x * 64;
  for (int idx = tid; idx < 25600; idx += 512) {
    int item = idx / 400, feat = idx - item * 400;
    xs[item * 401 + feat] = obs[(size_t)(i0 + item) * 400 + feat];
  }
  __syncthreads();
  int lane = tid & 63;
  int wv = tid >> 6;  // 0..7, wave-uniform
  const float* xrow = xs + lane * 401;
#pragma unroll 1
  for (int p = 0; p < 5; ++p) {
    float acc[2][5][2][2];
#pragma unroll
    for (int u = 0; u < 2; ++u) {
      float bv = bias[wv * 2 + u];
#pragma unroll
      for (int q = 0; q < 5; ++q)
#pragma unroll
        for (int ii = 0; ii < 2; ++ii)
#pragma unroll
          for (int jj = 0; jj < 2; ++jj) acc[u][q][ii][jj] = bv;
    }
#pragma unroll 1
    for (int c = 0; c < 4; ++c) {
      float rows[4][12];
#pragma unroll
      for (int rr = 0; rr < 4; ++rr) {
        int r = 2 * p - 1 + rr;
        rows[rr][0] = 0.f;
        rows[rr][11] = 0.f;
        if (r >= 0 && r <= 9) {
#pragma unroll
          for (int j = 0; j < 10; ++j) rows[rr][j + 1] = xrow[c * 100 + r * 10 + j];
        } else {
#pragma unroll
          for (int j = 0; j < 10; ++j) rows[rr][j + 1] = 0.f;
        }
      }
#pragma unroll
      for (int u = 0; u < 2; ++u) {
        int o = wv * 2 + u;
        const float* wp = w + o * 36 + c * 9;
        float w00 = wp[0], w01 = wp[1], w02 = wp[2];
        float w10 = wp[3], w11 = wp[4], w12 = wp[5];
        float w20 = wp[6], w21 = wp[7], w22 = wp[8];
#pragma unroll
        for (int q = 0; q < 5; ++q) {
#pragma unroll
          for (int ii = 0; ii < 2; ++ii) {
#pragma unroll
            for (int jj = 0; jj < 2; ++jj) {
              float a = acc[u][q][ii][jj];
              int cb = 2 * q + jj;
              a += rows[ii][cb] * w00 + rows[ii][cb + 1] * w01 + rows[ii][cb + 2] * w02;
              a += rows[ii + 1][cb] * w10 + rows[ii + 1][cb + 1] * w11 + rows[ii + 1][cb + 2] * w12;
              a += rows[ii + 2][cb] * w20 + rows[ii + 2][cb + 1] * w21 + rows[ii + 2][cb + 2] * w22;
              acc[u][q][ii][jj] = a;
            }
          }
        }
      }
    }
#pragma unroll
    for (int u = 0; u < 2; ++u) {
      int o = wv * 2 + u;
#pragma unroll
      for (int q = 0; q < 5; ++q) {
        float m = fmaxf(fmaxf(acc[u][q][0][0], acc[u][q][0][1]),
                        fmaxf(acc[u][q][1][0], acc[u][q][1][1]));
        m = fmaxf(m, 0.f);
        p1[(size_t)(o * 25 + p * 5 + q) * BT + i0 + lane] = m;
      }
    }
  }
}

// ================= K2: conv2 (SAME 3x3, 16->32) + relu + 2x2 maxpool ======
__global__ __launch_bounds__(256, 2)
void k2_conv2(const float* __restrict__ p1, const float* __restrict__ w,
              const float* __restrict__ bias, float* __restrict__ x) {
  int item = blockIdx.x * 256 + threadIdx.x;
  int oc = blockIdx.y;
  float acc[8][16];
#pragma unroll
  for (int o = 0; o < 8; ++o) {
    float bv = bias[oc * 8 + o];
#pragma unroll
    for (int pos = 0; pos < 16; ++pos) acc[o][pos] = bv;
  }
#pragma unroll 1
  for (int c = 0; c < 16; ++c) {
    float in[6][6];
#pragma unroll
    for (int t = 0; t < 6; ++t) { in[0][t] = 0.f; in[t][0] = 0.f; }
#pragma unroll
    for (int i = 0; i < 5; ++i)
#pragma unroll
      for (int j = 0; j < 5; ++j)
        in[i + 1][j + 1] = p1[(size_t)(c * 25 + i * 5 + j) * BT + item];
#pragma unroll
    for (int o = 0; o < 8; ++o) {
#pragma unroll
      for (int i = 0; i < 4; ++i)
#pragma unroll
        for (int j = 0; j < 4; ++j) {
          float a = acc[o][i * 4 + j];
#pragma unroll
          for (int dr = 0; dr < 3; ++dr)
#pragma unroll
            for (int dj = 0; dj < 3; ++dj)
              a += in[i + dr][j + dj] * w[((oc * 8 + o) * 16 + c) * 9 + dr * 3 + dj];
          acc[o][i * 4 + j] = a;
        }
    }
  }
#pragma unroll
  for (int o = 0; o < 8; ++o)
#pragma unroll
    for (int p = 0; p < 2; ++p)
#pragma unroll
      for (int q = 0; q < 2; ++q) {
        float m = fmaxf(fmaxf(acc[o][(2 * p) * 4 + 2 * q], acc[o][(2 * p) * 4 + 2 * q + 1]),
                        fmaxf(acc[o][(2 * p + 1) * 4 + 2 * q], acc[o][(2 * p + 1) * 4 + 2 * q + 1]));
        m = fmaxf(m, 0.f);
        x[(size_t)((oc * 8 + o) * 4 + p * 2 + q) * BT + item] = m;
      }
}

// ================= K3: fc1(+bn,relu) -> fc2(+bn,relu) -> eWih projection ===
__global__ __launch_bounds__(256, 2)
void k3_fc(const float* __restrict__ x,
           const float* __restrict__ f1w, const float* __restrict__ f1b,
           const float* __restrict__ bn1g, const float* __restrict__ bn1b,
           const float* __restrict__ f2w, const float* __restrict__ f2b,
           const float* __restrict__ bn2g, const float* __restrict__ bn2b,
           const float* __restrict__ eWih, const float* __restrict__ ebih,
           const float* __restrict__ ebhh, float* __restrict__ gx) {
  __shared__ float xs[128 * 64];
  __shared__ float ys[128 * 64];
  const float BNRS = 0.9999950000374997f;  // 1/sqrt(1+1e-5)
  int tid = threadIdx.x;
  int lane = tid & 63;
  int wv = __builtin_amdgcn_readfirstlane(tid >> 6);
  int i0 = blockIdx.x * 64;
#pragma unroll
  for (int r = 0; r < 32; ++r) {
    int k = r * 4 + (tid >> 6);
    xs[k * 64 + lane] = x[(size_t)k * BT + i0 + lane];
  }
  __syncthreads();
#pragma unroll 1
  for (int jj = 0; jj < 8; ++jj) {
    int j0 = wv * 32 + jj * 4;
    float a[4] = {0.f, 0.f, 0.f, 0.f};
#pragma unroll 8
    for (int k = 0; k < 128; ++k) {
      float xv = xs[k * 64 + lane];
#pragma unroll
      for (int u = 0; u < 4; ++u) a[u] += xv * f1w[(j0 + u) * 128 + k];
    }
#pragma unroll
    for (int u = 0; u < 4; ++u) {
      int j = j0 + u;
      float v = a[u] + f1b[j];
      v = bn1g[j] * v * BNRS + bn1b[j];
      ys[j * 64 + lane] = fmaxf(v, 0.f);
    }
  }
  __syncthreads();
#pragma unroll 1
  for (int jj = 0; jj < 4; ++jj) {
    int j0 = wv * 16 + jj * 4;
    float a[4] = {0.f, 0.f, 0.f, 0.f};
#pragma unroll 8
    for (int k = 0; k < 128; ++k) {
      float yv = ys[k * 64 + lane];
#pragma unroll
      for (int u = 0; u < 4; ++u) a[u] += yv * f2w[(j0 + u) * 128 + k];
    }
#pragma unroll
    for (int u = 0; u < 4; ++u) {
      int j = j0 + u;
      float v = a[u] + f2b[j];
      v = bn2g[j] * v * BNRS + bn2b[j];
      xs[j * 64 + lane] = fmaxf(v, 0.f);
    }
  }
  __syncthreads();
#pragma unroll 1
  for (int jj = 0; jj < 8; ++jj) {
    int j0 = wv * 32 + jj * 4;
    float a[4] = {0.f, 0.f, 0.f, 0.f};
#pragma unroll 8
    for (int k = 0; k < 64; ++k) {
      float zv = xs[k * 64 + lane];
#pragma unroll
      for (int u = 0; u < 4; ++u) a[u] += zv * eWih[(j0 + u) * 64 + k];
    }
#pragma unroll
    for (int u = 0; u < 4; ++u) {
      int j = j0 + u;
      gx[(size_t)j * BT + i0 + lane] = a[u] + ebih[j] + ebhh[j];
    }
  }
}

// ================= K4: encoder LSTM (T=100), one wave per batch ===========
__global__ __launch_bounds__(64, 4)
void k4_enc(const float* __restrict__ gx, const float* __restrict__ eWhh,
            float* __restrict__ dh, float* __restrict__ dc) {
  __shared__ float wT[32 * 128];  // [k][gate]
  int lane = threadIdx.x;
  int b = blockIdx.x;
#pragma unroll 1
  for (int r = 0; r < 64; ++r) {
    int idx = lane + r * 64;
    int g = idx & 127, k = idx >> 7;
    wT[k * 128 + g] = eWhh[g * 32 + k];
  }
  __syncthreads();
  float c = 0.f, h = 0.f;
  size_t base0 = (size_t)b * 100;
  float ga_n = gx[(size_t)lane * BT + base0];
  float gb_n = gx[(size_t)(lane + 64) * BT + base0];
  int xl = (lane & 31) + 32;
#pragma unroll 1
  for (int t = 0; t < 100; ++t) {
    float ga = ga_n, gb2 = gb_n;
    if (t < 99) {
      ga_n = gx[(size_t)lane * BT + base0 + t + 1];
      gb_n = gx[(size_t)(lane + 64) * BT + base0 + t + 1];
    }
#pragma unroll
    for (int k = 0; k < 32; ++k) {
      float hk = __shfl(h, k);
      ga += hk * wT[k * 128 + lane];
      gb2 += hk * wT[k * 128 + lane + 64];
    }
    float gaX = __shfl(ga, xl);   // gate lane+32 (f for lanes<32)
    float gbX = __shfl(gb2, xl);  // gate lane+96 (o for lanes<32)
    if (lane < 32) {
      float ig = sigf(ga);
      float fg = sigf(gaX);
      float gg = tanhf2(gb2);
      float og = sigf(gbX);
      c = fg * c + ig * gg;
      h = og * tanhf2(c);
    }
  }
  if (lane < 32) {
    dh[b * 32 + lane] = h;
    dc[b * 32 + lane] = c;
  }
}

// ====== K5: decoder LSTM (din==dh identity) + physics + Q/R LSTMs =========
__global__ __launch_bounds__(256, 2)
void k5_dec(const float* __restrict__ obs,
            const float* __restrict__ dWih, const float* __restrict__ dWhh,
            const float* __restrict__ dbih, const float* __restrict__ dbhh,
            const float* __restrict__ ow, const float* __restrict__ ob,
            const float* __restrict__ qWih, const float* __restrict__ qWhh,
            const float* __restrict__ qbih, const float* __restrict__ qbhh,
            const float* __restrict__ qfw, const float* __restrict__ qfb,
            const float* __restrict__ rWih, const float* __restrict__ rWhh,
            const float* __restrict__ rbih, const float* __restrict__ rbhh,
            const float* __restrict__ rfw, const float* __restrict__ rfb,
            const float* __restrict__ dh0, const float* __restrict__ dc0,
            float* __restrict__ traj, float* __restrict__ qdg, float* __restrict__ rdg) {
  __shared__ float dwT[32 * 128], qihT[24 * 128], qhhT[32 * 128], rihT[24 * 128], rhhT[32 * 128];
  __shared__ float owT[32 * 12], qfwT[32 * 24], rfwT[32 * 24];
  __shared__ float dbs[128], qbs[128], rbs[128];
  __shared__ float tL4[4 * 120];
  int tid = threadIdx.x;
  for (int idx = tid; idx < 4096; idx += 256) {
    int k = idx >> 7, g = idx & 127;
    dwT[idx] = dWih[g * 32 + k] + dWhh[g * 32 + k];  // din==dh every step
    qhhT[idx] = qWhh[g * 32 + k];
    rhhT[idx] = rWhh[g * 32 + k];
  }
  for (int idx = tid; idx < 3072; idx += 256) {
    int k = idx >> 7, g = idx & 127;
    qihT[idx] = qWih[g * 24 + k];
    rihT[idx] = rWih[g * 24 + k];
  }
  for (int idx = tid; idx < 384; idx += 256) {
    int k = idx / 12, j = idx - k * 12;
    owT[idx] = ow[j * 32 + k];
  }
  for (int idx = tid; idx < 768; idx += 256) {
    int k = idx / 24, j = idx - k * 24;
    qfwT[idx] = qfw[j * 32 + k];
    rfwT[idx] = rfw[j * 32 + k];
  }
  for (int idx = tid; idx < 128; idx += 256) {
    dbs[idx] = dbih[idx] + dbhh[idx];
    qbs[idx] = qbih[idx] + qbhh[idx];
    rbs[idx] = rbih[idx] + rbhh[idx];
  }
  __syncthreads();
  int lane = tid & 63, w = tid >> 6, b = blockIdx.x * 4 + w;
  float* tL = tL4 + w * 120;
  int xl = (lane & 31) + 32;
  int l12 = lane < 12 ? lane : 0;
  int l24 = lane < 24 ? lane : 0;
  float cc = 0.f, hh = 0.f;
  if (lane < 32) {
    hh = dh0[b * 32 + lane];
    cc = dc0[b * 32 + lane];
  }
  float aReg[5];
  // decoder: 5 steps
#pragma unroll 1
  for (int s = 0; s < 5; ++s) {
    float ga = dbs[lane], gb2 = dbs[lane + 64];
#pragma unroll
    for (int k = 0; k < 32; ++k) {
      float hk = __shfl(hh, k);
      ga += hk * dwT[k * 128 + lane];
      gb2 += hk * dwT[k * 128 + lane + 64];
    }
    float gaX = __shfl(ga, xl);
    float gbX = __shfl(gb2, xl);
    if (lane < 32) {
      float ig = sigf(ga), fg = sigf(gaX);
      float gg = tanhf2(gb2), og = sigf(gbX);
      cc = fg * cc + ig * gg;
      hh = og * tanhf2(cc);
    }
    float pa = ob[l12];
#pragma unroll
    for (int k = 0; k < 32; ++k) pa += __shfl(hh, k) * owT[k * 12 + l12];
    aReg[s] = pa;
  }
  // physics integration -> tL (traj)
  if (lane < 12) {
    int n = lane >> 1, d = lane & 1;
    float v0 = 0.f, p0 = 0.f;
    if (n == 0) {
      p0 = obs[(size_t)b * 40000 + 39600 + d];
      v0 = obs[(size_t)b * 40000 + 39600 + 2 + d];
    }
    float vc = v0, pc = p0;
#pragma unroll
    for (int s = 0; s < 5; ++s) {
      float a = aReg[s];
      vc += 0.1f * a;
      pc += vc * 0.1f + a * 0.005f;
      tL[s * 24 + n * 4 + d] = pc;
      tL[s * 24 + n * 4 + 2 + d] = vc;
    }
  }
  __syncthreads();
#pragma unroll
  for (int e = 0; e < 2; ++e) {
    int idx = lane + 64 * e;
    if (idx < 120) traj[(size_t)b * 120 + idx] = tL[idx];
  }
  // Q then R LSTM over traj
#pragma unroll 1
  for (int qr = 0; qr < 2; ++qr) {
    const float* ihT = qr ? rihT : qihT;
    const float* hhT = qr ? rhhT : qhhT;
    const float* bs = qr ? rbs : qbs;
    const float* fwT = qr ? rfwT : qfwT;
    const float* fbg = qr ? rfb : qfb;
    float* outg = qr ? rdg : qdg;
    hh = 0.f;
    cc = 0.f;
#pragma unroll 1
    for (int s = 0; s < 5; ++s) {
      float ga = bs[lane], gb2 = bs[lane + 64];
#pragma unroll
      for (int k = 0; k < 24; ++k) {
        float z = tL[s * 24 + k];
        ga += z * ihT[k * 128 + lane];
        gb2 += z * ihT[k * 128 + lane + 64];
      }
#pragma unroll
      for (int k = 0; k < 32; ++k) {
        float hk = __shfl(hh, k);
        ga += hk * hhT[k * 128 + lane];
        gb2 += hk * hhT[k * 128 + lane + 64];
      }
      float gaX = __shfl(ga, xl);
      float gbX = __shfl(gb2, xl);
      if (lane < 32) {
        float ig = sigf(ga), fg = sigf(gaX);
        float gg = tanhf2(gb2), og = sigf(gbX);
        cc = fg * cc + ig * gg;
        hh = og * tanhf2(cc);
      }
    }
    float qv = fbg[l24];
#pragma unroll
    for (int k = 0; k < 32; ++k) qv += __shfl(hh, k) * fwT[k * 24 + l24];
    if (lane < 24) outg[b * 24 + lane] = fabsf(qv);
  }
}

// ================= K6: Kalman filter, register-resident, one wave/batch ===
// Column-per-lane layout: lane j<24 holds P column j; aug matrix [S | Pm]
// columns on lanes 0..47. All cross-lane via __shfl; no LDS, no barriers.
// Uses S = Pm + diag(R) symmetric => solve(S,Pm^T) = S^{-1} Pm.
__global__ __launch_bounds__(64, 1)
void k6_kf(const float* __restrict__ obs, const float* __restrict__ traj,
           const float* __restrict__ qd, const float* __restrict__ rd,
           float* __restrict__ out) {
  int lane = threadIdx.x;
  int b = blockIdx.x;
  int l24 = (lane < 24) ? lane : 0;
  float sv = 0.f, qv = 0.f, rv = 0.f;
  if (lane < 24) {
    sv = (lane < 4) ? obs[(size_t)b * 40000 + 39600 + lane] : 0.f;
    qv = qd[b * 24 + lane];
    rv = rd[b * 24 + lane];
  }
  float p[24];
#pragma unroll
  for (int i = 0; i < 24; ++i) p[i] = (i == lane) ? 1.f : 0.f;
  const int srcPF = ((lane & 3) < 2) ? (lane + 2) : lane;  // in-range for all 64 lanes
  const int srcA = (lane < 24) ? lane : (lane - 24);
#pragma unroll 1
  for (int s = 0; s < 5; ++s) {
    // ---- s_m = F s ----
    float sshift = __shfl(sv, srcPF);
    float smv = sv + (((lane & 3) < 2) ? 0.1f * sshift : 0.f);
    // ---- P <- F P (row update, lane-local) ----
#pragma unroll
    for (int i = 0; i < 24; ++i)
      if ((i & 3) < 2) p[i] += 0.1f * p[i + 2];
    // ---- P <- P F^T (column update via shfl from col j+2) ----
#pragma unroll
    for (int i = 0; i < 24; ++i) {
      float t = __shfl(p[i], srcPF);
      if ((lane & 3) < 2) p[i] += 0.1f * t;
    }
    // ---- + Qm (diagonal) ----
#pragma unroll
    for (int i = 0; i < 24; ++i) p[i] += (i == lane) ? qv : 0.f;
    // ---- build aug [S | Pm]: lanes<24 S col, lanes 24..47 Pm col ----
    float a[24];
#pragma unroll
    for (int i = 0; i < 24; ++i) {
      float t = __shfl(p[i], srcA);
      a[i] = (lane < 24) ? (p[i] + ((i == lane) ? rv : 0.f)) : t;
    }
    // ---- Gauss-Jordan, no pivoting (S SPD) ----
#pragma unroll
    for (int k = 0; k < 24; ++k) {
      float piv = __shfl(a[k], k);
      float inv = 1.f / piv;
      float t = a[k] * inv;   // new row-k element in this column
#pragma unroll
      for (int i = 0; i < 24; ++i) {
        if (i != k) {
          float fi = __shfl(a[i], k);  // old ag[i][k] (lane k not yet updated)
          a[i] = fmaf(-fi, t, a[i]);
        }
      }
      a[k] = t;
    }
    // lanes 24+j now hold X = S^{-1} Pm column j;  K = X^T
    // ---- innovation & state update ----
    float zv = traj[(size_t)b * 120 + s * 24 + l24];
    float innv = zv - smv;  // valid on lanes<24 (shfl sources)
    float acc = 0.f;
#pragma unroll
    for (int m = 0; m < 24; ++m) acc += a[m] * __shfl(innv, m);
    float kupd = __shfl(acc, 24 + l24);  // lane i<24 pulls from lane 24+i
    sv = smv + kupd;
    if (lane < 24) out[(size_t)b * 120 + s * 24 + lane] = sv;
    // ---- P_new = Pm - X^T Pm : pn[i] = p[i] - sum_k X[k][i]*p[k] ----
    float pn[24];
#pragma unroll
    for (int i = 0; i < 24; ++i) {
      float acc2 = 0.f;
#pragma unroll
      for (int k = 0; k < 24; ++k) acc2 += __shfl(a[k], 24 + i) * p[k];
      pn[i] = p[i] - acc2;
    }
#pragma unroll
    for (int i = 0; i < 24; ++i) p[i] = pn[i];
  }
}

// =========================================================================
extern "C" void kernel_launch(void* const* d_in, const int* in_sizes, int n_in,
                              void* d_out, int out_size, void* d_ws, size_t ws_size,
                              hipStream_t stream) {
  (void)in_sizes; (void)n_in; (void)out_size; (void)ws_size;
  const float* obs  = (const float*)d_in[0];
  const float* c1w  = (const float*)d_in[1];
  const float* c1b  = (const float*)d_in[2];
  const float* c2w  = (const float*)d_in[3];
  const float* c2b  = (const float*)d_in[4];
  const float* f1w  = (const float*)d_in[5];
  const float* f1b  = (const float*)d_in[6];
  const float* bn1g = (const float*)d_in[7];
  const float* bn1b = (const float*)d_in[8];
  const float* f2w  = (const float*)d_in[9];
  const float* f2b  = (const float*)d_in[10];
  const float* bn2g = (const float*)d_in[11];
  const float* bn2b = (const float*)d_in[12];
  const float* eWih = (const float*)d_in[13];
  const float* eWhh = (const float*)d_in[14];
  const float* ebih = (const float*)d_in[15];
  const float* ebhh = (const float*)d_in[16];
  const float* dWih = (const float*)d_in[17];
  const float* dWhh = (const float*)d_in[18];
  const float* dbih = (const float*)d_in[19];
  const float* dbhh = (const float*)d_in[20];
  const float* ow   = (const float*)d_in[21];
  const float* ob   = (const float*)d_in[22];
  const float* qWih = (const float*)d_in[23];
  const float* qWhh = (const float*)d_in[24];
  const float* qbih = (const float*)d_in[25];
  const float* qbhh = (const float*)d_in[26];
  const float* qfw  = (const float*)d_in[27];
  const float* qfb  = (const float*)d_in[28];
  const float* rWih = (const float*)d_in[29];
  const float* rWhh = (const float*)d_in[30];
  const float* rbih = (const float*)d_in[31];
  const float* rbhh = (const float*)d_in[32];
  const float* rfw  = (const float*)d_in[33];
  const float* rfb  = (const float*)d_in[34];

  float* ws = (float*)d_ws;
  float* p1   = ws + P1_OFF;
  float* x    = ws + X_OFF;
  float* gx   = ws + GX_OFF;       // reuses p1 region (dead after k2)
  float* dh   = ws + SM_OFF;
  float* dc   = dh + 16384;
  float* traj = dh + 32768;
  float* qdg  = dh + 94208;
  float* rdg  = dh + 106496;
  float* out  = (float*)d_out;

  k1_conv1<<<800, 512, 0, stream>>>(obs, c1w, c1b, p1);
  k2_conv2<<<dim3(200, 4), 256, 0, stream>>>(p1, c2w, c2b, x);
  k3_fc<<<800, 256, 0, stream>>>(x, f1w, f1b, bn1g, bn1b, f2w, f2b, bn2g, bn2b,
                                 eWih, ebih, ebhh, gx);
  k4_enc<<<512, 64, 0, stream>>>(gx, eWhh, dh, dc);
  k5_dec<<<128, 256, 0, stream>>>(obs, dWih, dWhh, dbih, dbhh, ow, ob,
                                  qWih, qWhh, qbih, qbhh, qfw, qfb,
                                  rWih, rWhh, rbih, rbhh, rfw, rfb,
                                  dh, dc, traj, qdg, rdg);
  k6_kf<<<512, 64, 0, stream>>>(obs, traj, qdg, rdg, out);
}